// Round 15
// baseline (123.067 us; speedup 1.0000x reference)
//
#include <hip/hip_runtime.h>
#include <hip/hip_bf16.h>

typedef __bf16 bf16x8 __attribute__((ext_vector_type(8)));
typedef float  f32x4  __attribute__((ext_vector_type(4)));
typedef float  f32x16 __attribute__((ext_vector_type(16)));

#define BN_EPS 1e-5f
#define NROWS 131072
#define TPB 256               // 4 waves = 2 rg (32 rows) x 2 cg (128 cols)
#define BM 64                 // rows per block
#define NBLOCKS (NROWS / BM)  // 2048

// ws layout (bytes):
//   [0, 262144)        W0a packed bf16 (BN scale a folded) for 32x32x16 B-frags:
//                      flat = ((s*8 + t)*64 + lane)*8 + j
//                      n = t*32 + (lane&31); k = s*16 + (lane>>5)*8 + j ; s in [0,32)
//   [262144, 264192)   d_fused f32[512]   (c/a shift)
//   [264192, 265216)   D_fc    f32[256]   (fc shift incl b0, scaled by 1/A)
//   [265216, 267264)   W1a     f32[512]   (W1 * A_fc)

__global__ __launch_bounds__(256) void setup_kernel(
    const float* __restrict__ W0,
    const float* __restrict__ imu_gamma, const float* __restrict__ imu_beta,
    const float* __restrict__ imu_mean,  const float* __restrict__ imu_var,
    const float* __restrict__ frame_gamma, const float* __restrict__ frame_beta,
    const float* __restrict__ frame_mean,  const float* __restrict__ frame_var,
    const float* __restrict__ b0,
    const float* __restrict__ fc_gamma, const float* __restrict__ fc_beta,
    const float* __restrict__ fc_mean,  const float* __restrict__ fc_var,
    const float* __restrict__ W1,
    void* __restrict__ ws)
{
    __bf16* w0p   = (__bf16*)ws;
    float* d_fused = (float*)((char*)ws + 262144);
    float* D_fc    = d_fused + 512;
    float* W1a     = D_fc + 256;

    const int b = blockIdx.x;
    if (b < 512) {
        const int flat = b * 256 + threadIdx.x;
        const int j    = flat & 7;
        const int lane = (flat >> 3) & 63;
        const int t    = (flat >> 9) & 7;
        const int s    = flat >> 12;                  // 0..31
        const int n    = t * 32 + (lane & 31);
        const int k    = s * 16 + ((lane >> 5) << 3) + j;
        const float a = (k < 256)
            ? frame_gamma[k] * rsqrtf(frame_var[k] + BN_EPS)
            : imu_gamma[k - 256] * rsqrtf(imu_var[k - 256] + BN_EPS);
        w0p[flat] = (__bf16)(W0[n * 512 + k] * a);
    } else {
        const int t = threadIdx.x;
        const float af = frame_gamma[t] * rsqrtf(frame_var[t] + BN_EPS);
        d_fused[t]       = frame_beta[t] / af - frame_mean[t];
        const float ai = imu_gamma[t] * rsqrtf(imu_var[t] + BN_EPS);
        d_fused[256 + t] = imu_beta[t] / ai - imu_mean[t];
        const float A = fc_gamma[t] * rsqrtf(fc_var[t] + BN_EPS);
        D_fc[t] = fc_beta[t] / A + b0[t] - fc_mean[t];
        W1a[t]       = W1[t] * A;
        W1a[256 + t] = W1[256 + t] * A;
    }
}

__global__ __launch_bounds__(TPB, 3) void fusion_main(
    const float* __restrict__ frame, const float* __restrict__ imu,
    const float* __restrict__ b1,    const void* __restrict__ ws_c,
    float* __restrict__ out)
{
    const bf16x8* wsrc = (const bf16x8*)ws_c;   // B-frag idx = (s*8 + t)*64 + lane
    const float*  d_g  = (const float*)((const char*)ws_c + 262144);
    const float*  Dfc  = d_g + 512;
    const float*  W1a  = Dfc + 256;

    __shared__ float d_sh[512];         // BN shifts (broadcast reads)
    __shared__ float cbuf[2][BM][2];    // cross-cg fc1 combine

    const int tid  = threadIdx.x;
    const int wave = tid >> 6;
    const int lane = tid & 63;
    const int cg   = wave & 1;     // col group (128 cols)
    const int rg   = wave >> 1;    // row group (32 rows)
    const int row  = lane & 31;    // A-frag row / C col index
    const int hi   = lane >> 5;
    const size_t rowBlk = (size_t)blockIdx.x * BM;
    const size_t rowW   = rowBlk + rg * 32 + row;   // this lane's feature row

    d_sh[tid] = d_g[tid];
    d_sh[tid + 256] = d_g[tid + 256];
    __syncthreads();   // one of only two barriers in the kernel

    bf16x8 Bb[2][4];   // B fragments, 2-deep (L2-hot source)
    float4 Ff[3][2];   // feature rows, 3-deep (HBM source)

    auto loadB = [&](int s, int buf) {
        #pragma unroll
        for (int tt = 0; tt < 4; ++tt)
            Bb[buf][tt] = wsrc[(s * 8 + cg * 4 + tt) * 64 + lane];
    };
    auto loadF = [&](int s, int buf) {
        const float* srcp = (s < 16) ? frame : imu;   // fused = [frame | imu]
        const float* xp = srcp + rowW * 256 + (s & 15) * 16 + hi * 8;
        Ff[buf][0] = *(const float4*)xp;
        Ff[buf][1] = *(const float4*)(xp + 4);
    };

    // prologue: queue (oldest->newest) = [B0, F0, B1, F1, F2]
    loadB(0, 0); loadF(0, 0);
    loadB(1, 1); loadF(1, 1);
    loadF(2, 2);

    f32x16 acc[4];
    #pragma unroll
    for (int t = 0; t < 4; ++t)
        #pragma unroll
        for (int r = 0; r < 16; ++r) acc[t][r] = 0.f;

    // steady iter s: consume B[s%2], F[s%3]; then refill loadB(s+2) before
    // loadF(s+3) so the compiler's wait-for-B(s) implies F(s) (issued 3 iters
    // back) is retired -> F gets full 3-iter HBM cover, B 2-iter L2 cover.
    #pragma unroll
    for (int s = 0; s < 32; ++s) {
        const int kf = s * 16 + hi * 8;
        const f32x4 d0 = *(const f32x4*)(d_sh + kf);
        const f32x4 d1 = *(const f32x4*)(d_sh + kf + 4);
        const float4 x0 = Ff[s % 3][0], x1 = Ff[s % 3][1];
        bf16x8 af;
        af[0] = (__bf16)fmaxf(x0.x + d0[0], 0.f);
        af[1] = (__bf16)fmaxf(x0.y + d0[1], 0.f);
        af[2] = (__bf16)fmaxf(x0.z + d0[2], 0.f);
        af[3] = (__bf16)fmaxf(x0.w + d0[3], 0.f);
        af[4] = (__bf16)fmaxf(x1.x + d1[0], 0.f);
        af[5] = (__bf16)fmaxf(x1.y + d1[1], 0.f);
        af[6] = (__bf16)fmaxf(x1.z + d1[2], 0.f);
        af[7] = (__bf16)fmaxf(x1.w + d1[3], 0.f);
        #pragma unroll
        for (int tt = 0; tt < 4; ++tt)
            acc[tt] = __builtin_amdgcn_mfma_f32_32x32x16_bf16(af, Bb[s % 2][tt], acc[tt], 0, 0, 0);
        if (s < 30) loadB(s + 2, s % 2);       // refill after consumption (no WAR)
        if (s < 29) loadF(s + 3, s % 3);
    }

    // ---- epilogue (R14-verified): fc shift+ReLU + (W1*A) dot + combine + clamp ----
    // C/D (32x32): col = (cg*4+tt)*32 + row, row-in-tile = (r&3) + 8*(r>>2) + 4*hi
    float p0[16], p1[16];
    #pragma unroll
    for (int r = 0; r < 16; ++r) { p0[r] = 0.f; p1[r] = 0.f; }

    #pragma unroll
    for (int tt = 0; tt < 4; ++tt) {
        const int n = cg * 128 + tt * 32 + row;
        const float D = Dfc[n];
        const float w0n = W1a[n], w1n = W1a[256 + n];
        #pragma unroll
        for (int r = 0; r < 16; ++r) {
            const float h = fmaxf(acc[tt][r] + D, 0.f);
            p0[r] = fmaf(h, w0n, p0[r]);
            p1[r] = fmaf(h, w1n, p1[r]);
        }
    }
    #pragma unroll
    for (int off = 1; off < 32; off <<= 1) {   // reduce over 32 cols (never crosses hi)
        #pragma unroll
        for (int r = 0; r < 16; ++r) {
            p0[r] += __shfl_xor(p0[r], off, 64);
            p1[r] += __shfl_xor(p1[r], off, 64);
        }
    }
    if (row == 0) {   // lanes 0 and 32: 16 rows each
        #pragma unroll
        for (int r = 0; r < 16; ++r) {
            const int rb = (r & 3) + 8 * (r >> 2) + 4 * hi;
            cbuf[cg][rg * 32 + rb][0] = p0[r];
            cbuf[cg][rg * 32 + rb][1] = p1[r];
        }
    }
    __syncthreads();
    if (tid < BM) {
        const float v0 = fminf(fmaxf(cbuf[0][tid][0] + cbuf[1][tid][0] + b1[0], 0.f), 512.f);
        const float v1 = fminf(fmaxf(cbuf[0][tid][1] + cbuf[1][tid][1] + b1[1], 0.f), 384.f);
        *(float2*)(out + (rowBlk + tid) * 2) = make_float2(v0, v1);
    }
}

extern "C" void kernel_launch(void* const* d_in, const int* in_sizes, int n_in,
                              void* d_out, int out_size, void* d_ws, size_t ws_size,
                              hipStream_t stream) {
    const float* frame_feat  = (const float*)d_in[0];
    const float* imu_feat    = (const float*)d_in[1];
    const float* imu_gamma   = (const float*)d_in[2];
    const float* imu_beta    = (const float*)d_in[3];
    const float* imu_mean    = (const float*)d_in[4];
    const float* imu_var     = (const float*)d_in[5];
    const float* frame_gamma = (const float*)d_in[6];
    const float* frame_beta  = (const float*)d_in[7];
    const float* frame_mean  = (const float*)d_in[8];
    const float* frame_var   = (const float*)d_in[9];
    const float* W0          = (const float*)d_in[10];
    const float* b0          = (const float*)d_in[11];
    const float* fc_gamma    = (const float*)d_in[12];
    const float* fc_beta     = (const float*)d_in[13];
    const float* fc_mean     = (const float*)d_in[14];
    const float* fc_var      = (const float*)d_in[15];
    const float* W1          = (const float*)d_in[16];
    const float* b1          = (const float*)d_in[17];

    setup_kernel<<<513, 256, 0, stream>>>(
        W0, imu_gamma, imu_beta, imu_mean, imu_var,
        frame_gamma, frame_beta, frame_mean, frame_var,
        b0, fc_gamma, fc_beta, fc_mean, fc_var, W1, d_ws);

    fusion_main<<<NBLOCKS, TPB, 0, stream>>>(
        frame_feat, imu_feat, b1, d_ws, (float*)d_out);
}

// Round 17
// 73.000 us; speedup vs baseline: 1.6859x; 1.6859x over previous
//
#include <hip/hip_runtime.h>
#include <hip/hip_bf16.h>

typedef __bf16 bf16x8 __attribute__((ext_vector_type(8)));
typedef float  f32x4  __attribute__((ext_vector_type(4)));
typedef float  f32x16 __attribute__((ext_vector_type(16)));

#define BN_EPS 1e-5f
#define NROWS 131072
#define TPB 256               // 4 waves; wave owns 32 rows x all 256 cols
#define BM 128                // rows per block
#define NBLOCKS (NROWS / BM)  // 1024

#define WAITVM(N) asm volatile("s_waitcnt vmcnt(" #N ")" ::: "memory")

__device__ __forceinline__ void gll16(const void* g, void* l) {
    __builtin_amdgcn_global_load_lds(
        (const __attribute__((address_space(1))) void*)g,
        (__attribute__((address_space(3))) void*)l, 16, 0, 0);
}

// ws layout (bytes):
//   [0, 262144)        W0 packed bf16 for 32x32x16 B-frags:
//                      flat = ((s*8 + t)*64 + lane)*8 + j
//                      n = t*32 + (lane&31); k = s*16 + (lane>>5)*8 + j ; s in [0,32)
//   [262144, 264192)   a_fused f32[512]
//   [264192, 266240)   c_fused f32[512]
//   [266240, 267264)   A_fc f32[256]
//   [267264, 268288)   C_fc f32[256] (b0 folded in)

__global__ __launch_bounds__(256) void setup_kernel(
    const float* __restrict__ W0,
    const float* __restrict__ imu_gamma, const float* __restrict__ imu_beta,
    const float* __restrict__ imu_mean,  const float* __restrict__ imu_var,
    const float* __restrict__ frame_gamma, const float* __restrict__ frame_beta,
    const float* __restrict__ frame_mean,  const float* __restrict__ frame_var,
    const float* __restrict__ b0,
    const float* __restrict__ fc_gamma, const float* __restrict__ fc_beta,
    const float* __restrict__ fc_mean,  const float* __restrict__ fc_var,
    void* __restrict__ ws)
{
    __bf16* w0p    = (__bf16*)ws;
    float* a_fused = (float*)((char*)ws + 262144);
    float* c_fused = a_fused + 512;
    float* A_fc    = c_fused + 512;
    float* C_fc    = A_fc + 256;

    const int b = blockIdx.x;
    if (b < 512) {
        const int flat = b * 256 + threadIdx.x;
        const int j    = flat & 7;
        const int lane = (flat >> 3) & 63;
        const int t    = (flat >> 9) & 7;
        const int s    = flat >> 12;                  // 0..31
        const int n    = t * 32 + (lane & 31);
        const int k    = s * 16 + ((lane >> 5) << 3) + j;
        w0p[flat] = (__bf16)W0[n * 512 + k];
    } else {
        const int t = threadIdx.x;
        const float af = frame_gamma[t] * rsqrtf(frame_var[t] + BN_EPS);
        a_fused[t]       = af;
        c_fused[t]       = frame_beta[t] - frame_mean[t] * af;
        const float ai = imu_gamma[t] * rsqrtf(imu_var[t] + BN_EPS);
        a_fused[256 + t] = ai;
        c_fused[256 + t] = imu_beta[t] - imu_mean[t] * ai;
        const float A = fc_gamma[t] * rsqrtf(fc_var[t] + BN_EPS);
        A_fc[t] = A;
        C_fc[t] = fc_beta[t] - fc_mean[t] * A + A * b0[t];
    }
}

__global__ __launch_bounds__(TPB, 1) void fusion_main(
    const float* __restrict__ frame, const float* __restrict__ imu,
    const float* __restrict__ W1,    const float* __restrict__ b1,
    const void* __restrict__ ws_c,   float* __restrict__ out)
{
    const __bf16* w0p  = (const __bf16*)ws_c;
    const float*  a_g  = (const float*)((const char*)ws_c + 262144);
    const float*  c_g  = a_g + 512;
    const float*  A_fc = c_g + 512;
    const float*  C_fc = A_fc + 256;

    // 53.2 KB total -> 3 blocks/CU (three independent barrier domains)
    __shared__ __align__(16) __bf16 wpan[3][4096];   // 3 x 8 KB single-k-step W0 panels
    __shared__ __align__(16) float  ring[4][3][512]; // per-wave 3-slot feature ring (2 KB slots)
    __shared__ float asx[512], csx[512];

    const int tid  = threadIdx.x;
    const int wave = tid >> 6;
    const int lane = tid & 63;
    const int row  = lane & 31;   // A-frag row / C col index
    const int hi   = lane >> 5;
    const size_t rowBlk = (size_t)blockIdx.x * BM;
    const size_t rowW   = rowBlk + wave * 32;

    // chunk c = one k-step (k=16): 32 rows x 16 f32 = 2 KB = 2 gll.
    // physical granule p at slot-row r holds logical granule p ^ ((r>>1)&3).
    const int fr = lane >> 2;                         // 0..15
    const int fg = (lane & 3) ^ ((lane >> 3) & 3);    // logical granule this lane fetches

    auto issueF = [&](int c) {
        const int cc = (c < 31) ? c : 31;             // tail: dead slot re-load
        const int slot = c % 3;
        const float* srcp = (cc < 16) ? frame : imu;
        const int kb = (cc & 15) * 16;
        float* dstb = &ring[wave][slot][0];
        gll16(srcp + (rowW + fr) * 256 + kb + fg * 4, dstb);
        gll16(srcp + (rowW + 16 + fr) * 256 + kb + fg * 4, dstb + 256);
    };
    auto issueW = [&](int e) {
        const int ee = (e < 31) ? e : 31;             // tail: dead panel re-load
        const char* src = (const char*)w0p + ee * 8192 + wave * 1024 + lane * 16;
        char* dst = (char*)&wpan[e % 3][0] + wave * 1024;
        gll16(src, dst);
        gll16(src + 4096, dst + 4096);
    };

    // ---- prologue ----
    asx[tid] = a_g[tid];
    asx[tid + 256] = a_g[tid + 256];
    csx[tid] = c_g[tid];
    csx[tid + 256] = c_g[tid + 256];
    asm volatile("s_waitcnt vmcnt(0)" ::: "memory");   // clean vm queue for counted waits
    issueW(0);
    issueF(0);
    issueW(1);
    issueF(1);
    WAITVM(4);                    // retire W(0),F(0); queue = [W1,F1]
    asm volatile("s_waitcnt lgkmcnt(0)" ::: "memory");
    __builtin_amdgcn_s_barrier();

    f32x16 acc[8];
    #pragma unroll
    for (int t = 0; t < 8; ++t)
        #pragma unroll
        for (int r = 0; r < 16; ++r) acc[t][r] = 0.f;

    auto stepc = [&](int s) {
        const float* sb = &ring[wave][s % 3][0];
        const int sw = (row >> 1) & 3;
        const int g0 = hi * 2;
        const f32x4 x0 = *(const f32x4*)(sb + row * 16 + (((g0 + 0) ^ sw) << 2));
        const f32x4 x1 = *(const f32x4*)(sb + row * 16 + (((g0 + 1) ^ sw) << 2));
        const int kf = s * 16 + hi * 8;
        const f32x4 a0 = *(const f32x4*)(asx + kf);
        const f32x4 a1 = *(const f32x4*)(asx + kf + 4);
        const f32x4 c0 = *(const f32x4*)(csx + kf);
        const f32x4 c1 = *(const f32x4*)(csx + kf + 4);
        bf16x8 af;
        af[0] = (__bf16)fmaxf(fmaf(a0[0], x0[0], c0[0]), 0.f);
        af[1] = (__bf16)fmaxf(fmaf(a0[1], x0[1], c0[1]), 0.f);
        af[2] = (__bf16)fmaxf(fmaf(a0[2], x0[2], c0[2]), 0.f);
        af[3] = (__bf16)fmaxf(fmaf(a0[3], x0[3], c0[3]), 0.f);
        af[4] = (__bf16)fmaxf(fmaf(a1[0], x1[0], c1[0]), 0.f);
        af[5] = (__bf16)fmaxf(fmaf(a1[1], x1[1], c1[1]), 0.f);
        af[6] = (__bf16)fmaxf(fmaf(a1[2], x1[2], c1[2]), 0.f);
        af[7] = (__bf16)fmaxf(fmaf(a1[3], x1[3], c1[3]), 0.f);
        const __bf16* pan = &wpan[s % 3][0];
        __builtin_amdgcn_s_setprio(1);                 // T5: favor MFMA wave vs other blocks' staging
        #pragma unroll
        for (int t = 0; t < 8; ++t) {
            const bf16x8 bfr = *(const bf16x8*)(pan + (t * 64 + lane) * 8);
            acc[t] = __builtin_amdgcn_mfma_f32_32x32x16_bf16(af, bfr, acc[t], 0, 0, 0);
        }
        __builtin_amdgcn_s_setprio(0);
    };

    // steady phase s: entry queue [W(s+1), F(s+1)]  (both issued in phase s-1)
    //   +W(s+2) +F(s+2) -> stepc(s) -> WAITVM(4) retires W(s+1), F(s+1) -> barrier
    #pragma unroll
    for (int s = 0; s < 32; ++s) {
        issueW(s + 2);
        issueF(s + 2);
        stepc(s);
        WAITVM(4);
        __builtin_amdgcn_s_barrier();
    }
    WAITVM(0);   // drain dangling tail glls

    // ---- epilogue: fc BN+ReLU + fc1 + ReLU + clamp (wave-local) ----
    // C/D (32x32): col = t*32 + row, row-in-tile = (r&3) + 8*(r>>2) + 4*hi
    const float b1_0 = b1[0], b1_1 = b1[1];
    float p0[16], p1[16];
    #pragma unroll
    for (int r = 0; r < 16; ++r) { p0[r] = 0.f; p1[r] = 0.f; }

    #pragma unroll
    for (int t = 0; t < 8; ++t) {
        const int n = t * 32 + row;
        const float A = A_fc[n], C = C_fc[n];
        const float w0n = W1[n], w1n = W1[256 + n];
        #pragma unroll
        for (int r = 0; r < 16; ++r) {
            const float h = fmaxf(fmaf(A, acc[t][r], C), 0.f);
            p0[r] = fmaf(h, w0n, p0[r]);
            p1[r] = fmaf(h, w1n, p1[r]);
        }
    }
    #pragma unroll
    for (int off = 1; off < 32; off <<= 1) {
        #pragma unroll
        for (int r = 0; r < 16; ++r) {
            p0[r] += __shfl_xor(p0[r], off, 64);
            p1[r] += __shfl_xor(p1[r], off, 64);
        }
    }
    if (row == 0) {   // lanes 0 and 32 each write 16 rows
        #pragma unroll
        for (int r = 0; r < 16; ++r) {
            const int rbase = (r & 3) + 8 * (r >> 2) + 4 * hi;
            const float v0 = fminf(fmaxf(p0[r] + b1_0, 0.f), 512.f);
            const float v1 = fminf(fmaxf(p1[r] + b1_1, 0.f), 384.f);
            *(float2*)(out + (rowW + rbase) * 2) = make_float2(v0, v1);
        }
    }
}

extern "C" void kernel_launch(void* const* d_in, const int* in_sizes, int n_in,
                              void* d_out, int out_size, void* d_ws, size_t ws_size,
                              hipStream_t stream) {
    const float* frame_feat  = (const float*)d_in[0];
    const float* imu_feat    = (const float*)d_in[1];
    const float* imu_gamma   = (const float*)d_in[2];
    const float* imu_beta    = (const float*)d_in[3];
    const float* imu_mean    = (const float*)d_in[4];
    const float* imu_var     = (const float*)d_in[5];
    const float* frame_gamma = (const float*)d_in[6];
    const float* frame_beta  = (const float*)d_in[7];
    const float* frame_mean  = (const float*)d_in[8];
    const float* frame_var   = (const float*)d_in[9];
    const float* W0          = (const float*)d_in[10];
    const float* b0          = (const float*)d_in[11];
    const float* fc_gamma    = (const float*)d_in[12];
    const float* fc_beta     = (const float*)d_in[13];
    const float* fc_mean     = (const float*)d_in[14];
    const float* fc_var      = (const float*)d_in[15];
    const float* W1          = (const float*)d_in[16];
    const float* b1          = (const float*)d_in[17];

    setup_kernel<<<513, 256, 0, stream>>>(
        W0, imu_gamma, imu_beta, imu_mean, imu_var,
        frame_gamma, frame_beta, frame_mean, frame_var,
        b0, fc_gamma, fc_beta, fc_mean, fc_var, d_ws);

    fusion_main<<<NBLOCKS, TPB, 0, stream>>>(
        frame_feat, imu_feat, W1, b1, d_ws, (float*)d_out);
}